// Round 17
// baseline (434.268 us; speedup 1.0000x reference)
//
#include <hip/hip_runtime.h>

typedef __attribute__((ext_vector_type(8))) short short8;
typedef __attribute__((ext_vector_type(4))) float f32x4;

#define GLD_AS1 const __attribute__((address_space(1))) void*
#define GLD_AS3 __attribute__((address_space(3))) void*

__device__ __forceinline__ unsigned short f2bf(float f) {
  unsigned u = __builtin_bit_cast(unsigned, f);
  u += 0x7fffu + ((u >> 16) & 1u);   // round-to-nearest-even
  return (unsigned short)(u >> 16);
}
__device__ __forceinline__ float bf2f(unsigned short h) {
  return __builtin_bit_cast(float, (unsigned)h << 16);
}

// ---------------- fp32 -> bf16 convert: x AND the 3 weight matrices, one launch ----
__global__ void cvt_all(const float* __restrict__ x, const float* __restrict__ wq,
                        const float* __restrict__ wk, const float* __restrict__ wv,
                        unsigned short* __restrict__ xb, unsigned short* __restrict__ wcat) {
  const int nx = (4 * 4096 * 512) / 4;   // float4 granules of x
  const int nw = 3 * 65536;              // float4 granules of Wq|Wk|Wv
  int i = blockIdx.x * blockDim.x + threadIdx.x;
  const int st = gridDim.x * blockDim.x;
  for (; i < nx + nw; i += st) {
    float4 f;
    unsigned long long* dst;
    if (i < nx) {
      f = reinterpret_cast<const float4*>(x)[i];
      dst = reinterpret_cast<unsigned long long*>(xb) + i;
    } else {
      const int k = i - nx, seg = k >> 16, off = k & 65535;
      const float* s = (seg == 0) ? wq : (seg == 1) ? wk : wv;
      f = reinterpret_cast<const float4*>(s)[off];
      dst = reinterpret_cast<unsigned long long*>(wcat) + k;
    }
    unsigned long long p = (unsigned long long)f2bf(f.x)
        | ((unsigned long long)f2bf(f.y) << 16)
        | ((unsigned long long)f2bf(f.z) << 32)
        | ((unsigned long long)f2bf(f.w) << 48);
    *dst = p;
  }
}

// ---------------- fused QKV projection (R15-verified) ----------------
// Y[16384,1536] = xb[16384,512] @ Wcat[1536,512]^T ; Q rows PRE-SCALED by
// (1/sqrt(512))*log2(e). Grid (n=12, m=128) n-fastest for x-tile L2 reuse.
// Epilogue: acc -> LDS bounce tile (Vt blocks transposed) -> 16B coalesced stores.
__global__ __launch_bounds__(256) void qkv_gemm(
    const unsigned short* __restrict__ xb, const unsigned short* __restrict__ wcat,
    unsigned short* __restrict__ qb, unsigned short* __restrict__ kb,
    unsigned short* __restrict__ vtb) {
  __shared__ __align__(16) unsigned short lds_all[128 * 136];
  unsigned short* As = lds_all;
  unsigned short* Bs = lds_all + 128 * 64;
  const int tid = threadIdx.x, lane = tid & 63, w = tid >> 6;
  const int m0 = blockIdx.y * 128, n0 = blockIdx.x * 128;
  const int wr = w >> 1, wc = w & 1;
  const float QSCALE = 0.0637587085f;  // (1/sqrt(512)) * log2(e)

  f32x4 acc[4][4];
  const f32x4 z4 = {0.f, 0.f, 0.f, 0.f};
  #pragma unroll
  for (int a = 0; a < 4; ++a)
    #pragma unroll
    for (int c = 0; c < 4; ++c) acc[a][c] = z4;

  for (int it = 0; it < 8; ++it) {
    const int k0 = it * 64;
    #pragma unroll
    for (int c = 0; c < 4; ++c) {
      const int rbase = 32 * w + 8 * c;
      const int r = rbase + (lane >> 3);
      const int c16 = (lane & 7) ^ (r & 7);
      const unsigned short* ga = xb + (size_t)(m0 + r) * 512 + k0 + c16 * 8;
      const unsigned short* gb = wcat + (size_t)(n0 + r) * 512 + k0 + c16 * 8;
      __builtin_amdgcn_global_load_lds((GLD_AS1)ga, (GLD_AS3)&As[rbase * 64], 16, 0, 0);
      __builtin_amdgcn_global_load_lds((GLD_AS1)gb, (GLD_AS3)&Bs[rbase * 64], 16, 0, 0);
    }
    __syncthreads();
    #pragma unroll
    for (int ks = 0; ks < 2; ++ks) {
      const int ck = ks * 4 + (lane >> 4);
      short8 av[4], bv[4];
      #pragma unroll
      for (int fr = 0; fr < 4; ++fr) {
        const int rl = 64 * wr + 16 * fr + (lane & 15);
        av[fr] = *reinterpret_cast<const short8*>(&As[rl * 64 + ((ck ^ (rl & 7)) << 3)]);
      }
      #pragma unroll
      for (int fc = 0; fc < 4; ++fc) {
        const int rl = 64 * wc + 16 * fc + (lane & 15);
        bv[fc] = *reinterpret_cast<const short8*>(&Bs[rl * 64 + ((ck ^ (rl & 7)) << 3)]);
      }
      #pragma unroll
      for (int fr = 0; fr < 4; ++fr)
        #pragma unroll
        for (int fc = 0; fc < 4; ++fc)
          acc[fr][fc] = __builtin_amdgcn_mfma_f32_16x16x32_bf16(av[fr], bv[fc], acc[fr][fc], 0, 0, 0);
    }
    __syncthreads();
  }

  // ---- epilogue: fragments -> bounce tile (Vt transposed), then 16B stores ----
  const int which = n0 >> 9;  // uniform per block
  #pragma unroll
  for (int fr = 0; fr < 4; ++fr) {
    #pragma unroll
    for (int fc = 0; fc < 4; ++fc) {
      const int nl = 64 * wc + 16 * fc + (lane & 15);
      #pragma unroll
      for (int j = 0; j < 4; ++j) {
        const int mlr = 64 * wr + 16 * fr + (lane >> 4) * 4 + j;
        const float a = acc[fr][fc][j];
        const unsigned short v = f2bf(which == 0 ? a * QSCALE : a);
        if (which == 2) lds_all[nl * 136 + mlr] = v;   // transposed: row = d, col = s
        else            lds_all[mlr * 136 + nl] = v;   // row = m, col = n
      }
    }
  }
  __syncthreads();
  if (which == 2) {
    const size_t bidx = (size_t)(m0 >> 12);
    unsigned short* vb = vtb + (bidx * 512 + (n0 & 511)) * 4096 + (m0 & 4095);
    #pragma unroll
    for (int i = 0; i < 8; ++i) {
      const int cid = tid + 256 * i;          // 0..2047
      const int r = cid >> 4, c = cid & 15;   // r = local d row, c = s chunk
      const short8 v = *reinterpret_cast<const short8*>(&lds_all[r * 136 + c * 8]);
      *reinterpret_cast<short8*>(&vb[(size_t)r * 4096 + c * 8]) = v;
    }
  } else {
    unsigned short* ob = (which == 0) ? qb : kb;
    const int nbase = n0 & 511;
    #pragma unroll
    for (int i = 0; i < 8; ++i) {
      const int cid = tid + 256 * i;
      const int r = cid >> 4, c = cid & 15;   // r = local m row, c = n chunk
      const short8 v = *reinterpret_cast<const short8*>(&lds_all[r * 136 + c * 8]);
      *reinterpret_cast<short8*>(&ob[(size_t)(m0 + r) * 512 + nbase + c * 8]) = v;
    }
  }
}

// ---- barrier helpers (raw s_barrier + explicit counted waitcnt; rule-18 fences) ----
#define FENCE() __builtin_amdgcn_sched_barrier(0)
#define BAR_VM8()  do { FENCE(); asm volatile("s_waitcnt vmcnt(8) lgkmcnt(0)" ::: "memory"); \
                        FENCE(); __builtin_amdgcn_s_barrier(); FENCE(); } while (0)
#define BAR_VM0()  do { FENCE(); asm volatile("s_waitcnt vmcnt(0) lgkmcnt(0)" ::: "memory"); \
                        FENCE(); __builtin_amdgcn_s_barrier(); FENCE(); } while (0)

// ---------------- causal flash attention (R13 structure + V-prefetch depth 2) --------
// Split-KV (two blocks per (b,qt)), no-max exp2-domain softmax, Ks LDS double
// buffer, P_lds double buffer, vreg DOUBLE buffer (V(t) -> vreg[t&1], issued at the
// TOP of iter t, consumed by PV(t) one full iteration later -> V-source latency
// fully hidden). ONE barrier per KV tile with counted vmcnt(8):
//   [stage K(t+2) | V(t)->vreg[t&1] | PV(t-1) from vreg[(t-1)&1] | mask(t)
//    | softmax(t)->P[t&1] | QK(t+1)]  ->  s_waitcnt vmcnt(8) lgkmcnt(0); s_barrier
// vmcnt audit: stage's 8 loads issue FIRST (fence-pinned) -> vmcnt(8) drains stage,
// leaves this iter's V (8 loads) in flight; PV's compiler dep-wait catches them.
__global__ __launch_bounds__(512, 2) void attn_fwd(
    const unsigned short* __restrict__ qg, const unsigned short* __restrict__ kg,
    const unsigned short* __restrict__ vtg,
    float* __restrict__ out0,            // [B][S][512] fp32 unnormalized (half 0)
    unsigned short* __restrict__ out1,   // [B][S][512] bf16 unnormalized (half 1)
    float* __restrict__ ml) {            // [4][B*S] : m0,l0,m1,l1  (log2 domain; m==0)
  __shared__ __align__(16) unsigned short Ks[2][64 * 512];   // 128KB dbuf (tile k -> buf k&1)
  __shared__ __align__(16) unsigned short P_lds[2][64][72];  // 18.4KB dbuf (tile t -> buf t&1)
  __shared__ __align__(16) float psums[2][64];               // epilogue l exchange

  const int tid = threadIdx.x, lane = tid & 63, w = tid >> 6;
  const int idx = blockIdx.x;            // 0..511
  const int qt = 63 - (idx >> 3);        // LPT: big qt first
  const int b = (idx >> 1) & 3;
  const int half = idx & 1;
  const int nkt = qt + 1;
  const int kt0 = half ? (nkt >> 1) : 0;
  const int kt1 = half ? nkt : (nkt >> 1);
  const int q0 = qt * 64;

  const unsigned short* Qb  = qg  + (size_t)b * 4096 * 512;
  const unsigned short* Kb  = kg  + (size_t)b * 4096 * 512;
  const unsigned short* Vtb = vtg + (size_t)b * 512 * 4096;

  const int wr = w & 3, wc = w >> 2, g = lane >> 4, dw = w * 64;
  const int rbase = 16 * wr + 4 * g;     // this lane's 4 S-rows: rbase+j

  // Q hoist (already scaled by scale*log2e): 16 x short8 = 64 VGPR
  short8 qreg[16];
  {
    const unsigned short* qrow = Qb + (size_t)(q0 + 16 * wr + (lane & 15)) * 512 + (lane >> 4) * 8;
    #pragma unroll
    for (int ks = 0; ks < 16; ++ks)
      qreg[ks] = *reinterpret_cast<const short8*>(qrow + ks * 32);
  }

  const f32x4 z4 = {0.f, 0.f, 0.f, 0.f};
  f32x4 oacc[4][4];
  #pragma unroll
  for (int fr = 0; fr < 4; ++fr)
    #pragma unroll
    for (int fc = 0; fc < 4; ++fc) oacc[fr][fc] = z4;

  float l_run[4];
  #pragma unroll
  for (int j = 0; j < 4; ++j) l_run[j] = 0.f;

  short8 vregA[2][4], vregB[2][4];   // V double buffer: tile t -> (t&1 ? B : A)
  f32x4 sacc_cur[2], sacc_nxt[2];

#define STAGE_K(kt_) do {                                                                \
    _Pragma("unroll")                                                                    \
    for (int r8 = 0; r8 < 8; ++r8) {                                                     \
      const int r_ = r8 * 8 + w;                                                         \
      const unsigned short* g_ = Kb + (size_t)((kt_) * 64 + r_) * 512 + (lane ^ (r_ & 7)) * 8; \
      __builtin_amdgcn_global_load_lds((GLD_AS1)g_, (GLD_AS3)&Ks[(kt_) & 1][r_ * 512], 16, 0, 0); \
    }                                                                                    \
  } while (0)

#define LOAD_V(kv0_, vr_) do {                                                           \
    _Pragma("unroll")                                                                    \
    for (int ks = 0; ks < 2; ++ks)                                                       \
      _Pragma("unroll")                                                                  \
      for (int fc = 0; fc < 4; ++fc)                                                     \
        vr_[ks][fc] = *reinterpret_cast<const short8*>(                                  \
            Vtb + (size_t)(dw + 16 * fc + (lane & 15)) * 4096 + (kv0_) + ks * 32 +       \
            (lane >> 4) * 8);                                                            \
  } while (0)

#define QK_TILE(buf_, S_) do {                                                           \
    _Pragma("unroll")                                                                    \
    for (int ks = 0; ks < 16; ++ks) {                                                    \
      const int ck = ks * 4 + (lane >> 4);                                               \
      _Pragma("unroll")                                                                  \
      for (int fc = 0; fc < 2; ++fc) {                                                   \
        const int rl = 32 * wc + 16 * fc + (lane & 15);                                  \
        const short8 bv = *reinterpret_cast<const short8*>(                              \
            &Ks[buf_][rl * 512 + ((ck ^ (rl & 7)) << 3)]);                               \
        S_[fc] = __builtin_amdgcn_mfma_f32_16x16x32_bf16(qreg[ks], bv, S_[fc], 0, 0, 0); \
      }                                                                                  \
    }                                                                                    \
  } while (0)

#define PV_STEP(pb_, vr_) do {                                                           \
    _Pragma("unroll")                                                                    \
    for (int ks = 0; ks < 2; ++ks) {                                                     \
      short8 av[4];                                                                      \
      _Pragma("unroll")                                                                  \
      for (int fr = 0; fr < 4; ++fr)                                                     \
        av[fr] = *reinterpret_cast<const short8*>(                                       \
            &P_lds[pb_][16 * fr + (lane & 15)][ks * 32 + (lane >> 4) * 8]);              \
      __builtin_amdgcn_s_setprio(1);                                                     \
      _Pragma("unroll")                                                                  \
      for (int fr = 0; fr < 4; ++fr)                                                     \
        _Pragma("unroll")                                                                \
        for (int fc = 0; fc < 4; ++fc)                                                   \
          oacc[fr][fc] = __builtin_amdgcn_mfma_f32_16x16x32_bf16(av[fr], vr_[ks][fc],    \
                                                                 oacc[fr][fc], 0, 0, 0);\
      __builtin_amdgcn_s_setprio(0);                                                     \
    }                                                                                    \
  } while (0)

  if (kt0 < kt1) {
    // ---- prologue ----
    STAGE_K(kt0);
    const bool two = (kt0 + 1 < kt1);
    if (two) STAGE_K(kt0 + 1);
    FENCE();
    if (two) { asm volatile("s_waitcnt vmcnt(8)" ::: "memory"); }
    else     { asm volatile("s_waitcnt vmcnt(0)" ::: "memory"); }
    FENCE();
    __builtin_amdgcn_s_barrier();
    FENCE();
    sacc_cur[0] = z4; sacc_cur[1] = z4;
    QK_TILE(kt0 & 1, sacc_cur);
    // full drain once: covers stage(kt0+1) so the loop's QK(kt0+1) is safe, and
    // protects Ks[kt0&1] from the loop's first stage.
    BAR_VM0();

    for (int t = kt0; t < kt1; ++t) {
      // 1) stage(t+2) -> Ks[t&1]; pinned first in vm issue order
      if (t + 2 < kt1) STAGE_K(t + 2);
      FENCE();
      // 2) V(t) -> vreg[t&1] (alternate buffer: no WAR vs PV(t-1) below); consumed
      //    by PV(t) a full iteration later.
      const int kv0 = t * 64;
      if (t & 1) LOAD_V(kv0, vregB); else LOAD_V(kv0, vregA);
      // 3) PV(t-1) from vreg[(t-1)&1]
      if (t > kt0) {
        if ((t - 1) & 1) PV_STEP((t - 1) & 1, vregB); else PV_STEP((t - 1) & 1, vregA);
      }
      // 4) causal mask (diagonal tile only)
      if (t == qt) {
        #pragma unroll
        for (int fc = 0; fc < 2; ++fc) {
          const int col = 32 * wc + 16 * fc + (lane & 15);
          #pragma unroll
          for (int j = 0; j < 4; ++j)
            if (col > rbase + j) sacc_cur[fc][j] = -1e30f;
        }
      }
      // 5) softmax (no-max, exp2 domain) -> P_lds[t&1]
      {
        const int colb = 32 * wc + (lane & 15);
        #pragma unroll
        for (int j = 0; j < 4; ++j) {
          const float p0 = __builtin_amdgcn_exp2f(sacc_cur[0][j]);
          const float p1 = __builtin_amdgcn_exp2f(sacc_cur[1][j]);
          l_run[j] += p0 + p1;
          P_lds[t & 1][rbase + j][colb]      = f2bf(p0);
          P_lds[t & 1][rbase + j][colb + 16] = f2bf(p1);
        }
      }
      // 6) QK(t+1) from Ks[(t+1)&1] (staged at iter t-1, drained at its barrier)
      if (t + 1 < kt1) {
        sacc_nxt[0] = z4; sacc_nxt[1] = z4;
        __builtin_amdgcn_s_setprio(1);
        QK_TILE((t + 1) & 1, sacc_nxt);
        __builtin_amdgcn_s_setprio(0);
        sacc_cur[0] = sacc_nxt[0]; sacc_cur[1] = sacc_nxt[1];
      }
      // 7) single barrier: drain stage(t+2) (oldest 8), keep V(t) in flight
      BAR_VM8();
    }
    // tail: PV for the last tile
    if ((kt1 - 1) & 1) PV_STEP((kt1 - 1) & 1, vregB); else PV_STEP((kt1 - 1) & 1, vregA);
  }

  // ---- epilogue: reduce l across 16 lanes, then across wc; write O' and (m=0,l) ----
  #pragma unroll
  for (int j = 0; j < 4; ++j) {
    l_run[j] += __shfl_xor(l_run[j], 1);
    l_run[j] += __shfl_xor(l_run[j], 2);
    l_run[j] += __shfl_xor(l_run[j], 4);
    l_run[j] += __shfl_xor(l_run[j], 8);
  }
  if ((lane & 15) == 0) {
    f32x4 l4 = {l_run[0], l_run[1], l_run[2], l_run[3]};
    *reinterpret_cast<f32x4*>(&psums[wc][rbase]) = l4;
  }
  __syncthreads();
  if ((lane & 15) == 0 && wc == 0) {
    const int rg = b * 4096 + q0 + rbase;
    const f32x4 la = *reinterpret_cast<const f32x4*>(&psums[0][rbase]);
    const f32x4 lb = *reinterpret_cast<const f32x4*>(&psums[1][rbase]);
    f32x4 m4 = {0.f, 0.f, 0.f, 0.f};   // fixed log2-domain max
    f32x4 l4 = {la[0] + lb[0], la[1] + lb[1], la[2] + lb[2], la[3] + lb[3]};
    *reinterpret_cast<f32x4*>(&ml[(half * 2) * 16384 + rg])     = m4;
    *reinterpret_cast<f32x4*>(&ml[(half * 2 + 1) * 16384 + rg]) = l4;
  }
  if (half == 0) {
    float* ob = out0 + (size_t)b * 4096 * 512;
    #pragma unroll
    for (int fr = 0; fr < 4; ++fr)
      #pragma unroll
      for (int j = 0; j < 4; ++j) {
        const int row = 16 * fr + (lane >> 4) * 4 + j;
        #pragma unroll
        for (int fc = 0; fc < 4; ++fc)
          ob[(size_t)(q0 + row) * 512 + dw + 16 * fc + (lane & 15)] = oacc[fr][fc][j];
      }
  } else {
    unsigned short* ob = out1 + (size_t)b * 4096 * 512;
    #pragma unroll
    for (int fr = 0; fr < 4; ++fr)
      #pragma unroll
      for (int j = 0; j < 4; ++j) {
        const int row = 16 * fr + (lane >> 4) * 4 + j;
        #pragma unroll
        for (int fc = 0; fc < 4; ++fc)
          ob[(size_t)(q0 + row) * 512 + dw + 16 * fc + (lane & 15)] = f2bf(oacc[fr][fc][j]);
      }
  }
#undef STAGE_K
#undef LOAD_V
#undef QK_TILE
#undef PV_STEP
}

// ---------------- merge the two KV-halves ----------------
__global__ void attn_merge(float* __restrict__ out, const unsigned short* __restrict__ o1,
                           const float* __restrict__ ml) {
  const int total = 16384 * 128;  // float4 granules
  int i = blockIdx.x * blockDim.x + threadIdx.x;
  const int st = gridDim.x * blockDim.x;
  for (; i < total; i += st) {
    const int r = i >> 7;
    const float m0 = ml[r], l0 = ml[16384 + r];
    const float m1 = ml[2 * 16384 + r], l1 = ml[3 * 16384 + r];
    const float m = fmaxf(m0, m1);
    const float a0 = __builtin_amdgcn_exp2f(m0 - m), a1 = __builtin_amdgcn_exp2f(m1 - m);
    const float inv = 1.0f / (a0 * l0 + a1 * l1);  // half1 includes diagonal -> l1 > 0
    const float s0 = a0 * inv, s1 = a1 * inv;
    float4 v0 = reinterpret_cast<const float4*>(out)[i];
    ushort4 v1 = reinterpret_cast<const ushort4*>(o1)[i];
    float4 o;
    o.x = v0.x * s0 + bf2f(v1.x) * s1;
    o.y = v0.y * s0 + bf2f(v1.y) * s1;
    o.z = v0.z * s0 + bf2f(v1.z) * s1;
    o.w = v0.w * s0 + bf2f(v1.w) * s1;
    reinterpret_cast<float4*>(out)[i] = o;
  }
}

extern "C" void kernel_launch(void* const* d_in, const int* in_sizes, int n_in,
                              void* d_out, int out_size, void* d_ws, size_t ws_size,
                              hipStream_t stream) {
  const float* x  = (const float*)d_in[0];
  const float* wq = (const float*)d_in[1];
  const float* wk = (const float*)d_in[2];
  const float* wv = (const float*)d_in[3];

  // workspace layout (~68MB):
  // [0,16MB)    x bf16 [16384][512]  -- later REUSED as half1 partial O' (bf16)
  // [16,17.5MB) Wcat bf16 [1536][512]
  // [18,19MB)   ml float [4][16384]
  // [20,36MB)   Q bf16   [36,52MB) K bf16   [52,68MB) V^T bf16 [b][d][s]
  char* ws = (char*)d_ws;
  unsigned short* xb   = (unsigned short*)(ws);
  unsigned short* wcat = (unsigned short*)(ws + (16u << 20));
  float*          mlp  = (float*)(ws + (18u << 20));
  unsigned short* qb   = (unsigned short*)(ws + (20u << 20));
  unsigned short* kb   = (unsigned short*)(ws + (36u << 20));
  unsigned short* vtb  = (unsigned short*)(ws + (52u << 20));

  cvt_all<<<2048, 256, 0, stream>>>(x, wq, wk, wv, xb, wcat);

  qkv_gemm<<<dim3(12, 128), 256, 0, stream>>>(xb, wcat, qb, kb, vtb);

  // split-KV attention (R13 structure + V dbuf prefetch): 512 LPT blocks + merge.
  attn_fwd<<<512, 512, 0, stream>>>(qb, kb, vtb, (float*)d_out, xb, mlp);
  attn_merge<<<2048, 256, 0, stream>>>((float*)d_out, xb, mlp);
}

// Round 18
// 183.921 us; speedup vs baseline: 2.3612x; 2.3612x over previous
//
#include <hip/hip_runtime.h>

typedef __attribute__((ext_vector_type(8))) short short8;
typedef __attribute__((ext_vector_type(4))) float f32x4;

#define GLD_AS1 const __attribute__((address_space(1))) void*
#define GLD_AS3 __attribute__((address_space(3))) void*

__device__ __forceinline__ unsigned short f2bf(float f) {
  unsigned u = __builtin_bit_cast(unsigned, f);
  u += 0x7fffu + ((u >> 16) & 1u);   // round-to-nearest-even
  return (unsigned short)(u >> 16);
}
__device__ __forceinline__ float bf2f(unsigned short h) {
  return __builtin_bit_cast(float, (unsigned)h << 16);
}

// ---------------- fp32 -> bf16 convert: x AND the 3 weight matrices, one launch ----
__global__ void cvt_all(const float* __restrict__ x, const float* __restrict__ wq,
                        const float* __restrict__ wk, const float* __restrict__ wv,
                        unsigned short* __restrict__ xb, unsigned short* __restrict__ wcat) {
  const int nx = (4 * 4096 * 512) / 4;   // float4 granules of x
  const int nw = 3 * 65536;              // float4 granules of Wq|Wk|Wv
  int i = blockIdx.x * blockDim.x + threadIdx.x;
  const int st = gridDim.x * blockDim.x;
  for (; i < nx + nw; i += st) {
    float4 f;
    unsigned long long* dst;
    if (i < nx) {
      f = reinterpret_cast<const float4*>(x)[i];
      dst = reinterpret_cast<unsigned long long*>(xb) + i;
    } else {
      const int k = i - nx, seg = k >> 16, off = k & 65535;
      const float* s = (seg == 0) ? wq : (seg == 1) ? wk : wv;
      f = reinterpret_cast<const float4*>(s)[off];
      dst = reinterpret_cast<unsigned long long*>(wcat) + k;
    }
    unsigned long long p = (unsigned long long)f2bf(f.x)
        | ((unsigned long long)f2bf(f.y) << 16)
        | ((unsigned long long)f2bf(f.z) << 32)
        | ((unsigned long long)f2bf(f.w) << 48);
    *dst = p;
  }
}

// ---------------- fused QKV projection (R15-verified) ----------------
// Y[16384,1536] = xb[16384,512] @ Wcat[1536,512]^T ; Q rows PRE-SCALED by
// (1/sqrt(512))*log2(e). Grid (n=12, m=128) n-fastest for x-tile L2 reuse.
// Epilogue: acc -> LDS bounce tile (Vt blocks transposed) -> 16B coalesced stores.
__global__ __launch_bounds__(256) void qkv_gemm(
    const unsigned short* __restrict__ xb, const unsigned short* __restrict__ wcat,
    unsigned short* __restrict__ qb, unsigned short* __restrict__ kb,
    unsigned short* __restrict__ vtb) {
  __shared__ __align__(16) unsigned short lds_all[128 * 136];
  unsigned short* As = lds_all;
  unsigned short* Bs = lds_all + 128 * 64;
  const int tid = threadIdx.x, lane = tid & 63, w = tid >> 6;
  const int m0 = blockIdx.y * 128, n0 = blockIdx.x * 128;
  const int wr = w >> 1, wc = w & 1;
  const float QSCALE = 0.0637587085f;  // (1/sqrt(512)) * log2(e)

  f32x4 acc[4][4];
  const f32x4 z4 = {0.f, 0.f, 0.f, 0.f};
  #pragma unroll
  for (int a = 0; a < 4; ++a)
    #pragma unroll
    for (int c = 0; c < 4; ++c) acc[a][c] = z4;

  for (int it = 0; it < 8; ++it) {
    const int k0 = it * 64;
    #pragma unroll
    for (int c = 0; c < 4; ++c) {
      const int rbase = 32 * w + 8 * c;
      const int r = rbase + (lane >> 3);
      const int c16 = (lane & 7) ^ (r & 7);
      const unsigned short* ga = xb + (size_t)(m0 + r) * 512 + k0 + c16 * 8;
      const unsigned short* gb = wcat + (size_t)(n0 + r) * 512 + k0 + c16 * 8;
      __builtin_amdgcn_global_load_lds((GLD_AS1)ga, (GLD_AS3)&As[rbase * 64], 16, 0, 0);
      __builtin_amdgcn_global_load_lds((GLD_AS1)gb, (GLD_AS3)&Bs[rbase * 64], 16, 0, 0);
    }
    __syncthreads();
    #pragma unroll
    for (int ks = 0; ks < 2; ++ks) {
      const int ck = ks * 4 + (lane >> 4);
      short8 av[4], bv[4];
      #pragma unroll
      for (int fr = 0; fr < 4; ++fr) {
        const int rl = 64 * wr + 16 * fr + (lane & 15);
        av[fr] = *reinterpret_cast<const short8*>(&As[rl * 64 + ((ck ^ (rl & 7)) << 3)]);
      }
      #pragma unroll
      for (int fc = 0; fc < 4; ++fc) {
        const int rl = 64 * wc + 16 * fc + (lane & 15);
        bv[fc] = *reinterpret_cast<const short8*>(&Bs[rl * 64 + ((ck ^ (rl & 7)) << 3)]);
      }
      #pragma unroll
      for (int fr = 0; fr < 4; ++fr)
        #pragma unroll
        for (int fc = 0; fc < 4; ++fc)
          acc[fr][fc] = __builtin_amdgcn_mfma_f32_16x16x32_bf16(av[fr], bv[fc], acc[fr][fc], 0, 0, 0);
    }
    __syncthreads();
  }

  // ---- epilogue: fragments -> bounce tile (Vt transposed), then 16B stores ----
  const int which = n0 >> 9;  // uniform per block
  #pragma unroll
  for (int fr = 0; fr < 4; ++fr) {
    #pragma unroll
    for (int fc = 0; fc < 4; ++fc) {
      const int nl = 64 * wc + 16 * fc + (lane & 15);
      #pragma unroll
      for (int j = 0; j < 4; ++j) {
        const int mlr = 64 * wr + 16 * fr + (lane >> 4) * 4 + j;
        const float a = acc[fr][fc][j];
        const unsigned short v = f2bf(which == 0 ? a * QSCALE : a);
        if (which == 2) lds_all[nl * 136 + mlr] = v;   // transposed: row = d, col = s
        else            lds_all[mlr * 136 + nl] = v;   // row = m, col = n
      }
    }
  }
  __syncthreads();
  if (which == 2) {
    const size_t bidx = (size_t)(m0 >> 12);
    unsigned short* vb = vtb + (bidx * 512 + (n0 & 511)) * 4096 + (m0 & 4095);
    #pragma unroll
    for (int i = 0; i < 8; ++i) {
      const int cid = tid + 256 * i;          // 0..2047
      const int r = cid >> 4, c = cid & 15;   // r = local d row, c = s chunk
      const short8 v = *reinterpret_cast<const short8*>(&lds_all[r * 136 + c * 8]);
      *reinterpret_cast<short8*>(&vb[(size_t)r * 4096 + c * 8]) = v;
    }
  } else {
    unsigned short* ob = (which == 0) ? qb : kb;
    const int nbase = n0 & 511;
    #pragma unroll
    for (int i = 0; i < 8; ++i) {
      const int cid = tid + 256 * i;
      const int r = cid >> 4, c = cid & 15;   // r = local m row, c = n chunk
      const short8 v = *reinterpret_cast<const short8*>(&lds_all[r * 136 + c * 8]);
      *reinterpret_cast<short8*>(&ob[(size_t)(m0 + r) * 512 + nbase + c * 8]) = v;
    }
  }
}

// ---- barrier helpers (raw s_barrier + explicit counted waitcnt; rule-18 fences) ----
#define FENCE() __builtin_amdgcn_sched_barrier(0)
#define BAR_VM8()  do { FENCE(); asm volatile("s_waitcnt vmcnt(8) lgkmcnt(0)" ::: "memory"); \
                        FENCE(); __builtin_amdgcn_s_barrier(); FENCE(); } while (0)
#define BAR_VM0()  do { FENCE(); asm volatile("s_waitcnt vmcnt(0) lgkmcnt(0)" ::: "memory"); \
                        FENCE(); __builtin_amdgcn_s_barrier(); FENCE(); } while (0)

// ---------------- causal flash attention (R13/R15-verified: 123us) ----------------
// Split-KV (two blocks per (b,qt)), no-max exp2-domain softmax (m fixed = 0, exact),
// Ks LDS double buffer, P_lds double buffer, ONE barrier per KV tile with counted
// vmcnt(8):
//   [stage K(t+2) | PV(t-1) vreg=V(t-1) | mask(t) | softmax(t)->P[t&1]
//    | V(t)->vreg | QK(t+1)]  ->  s_waitcnt vmcnt(8) lgkmcnt(0); s_barrier
// Register budget note (R7/R16/R17 lessons): qreg 64 + vreg 32 + oacc 64 AGPR is
// ~25 VGPRs under the spill cliff at 2 waves/SIMD — do NOT add register state.
__global__ __launch_bounds__(512, 2) void attn_fwd(
    const unsigned short* __restrict__ qg, const unsigned short* __restrict__ kg,
    const unsigned short* __restrict__ vtg,
    float* __restrict__ out0,            // [B][S][512] fp32 unnormalized (half 0)
    unsigned short* __restrict__ out1,   // [B][S][512] bf16 unnormalized (half 1)
    float* __restrict__ ml) {            // [4][B*S] : m0,l0,m1,l1  (m==0 by construction)
  __shared__ __align__(16) unsigned short Ks[2][64 * 512];   // 128KB dbuf (tile k -> buf k&1)
  __shared__ __align__(16) unsigned short P_lds[2][64][72];  // 18.4KB dbuf (tile t -> buf t&1)
  __shared__ __align__(16) float psums[2][64];               // epilogue l exchange

  const int tid = threadIdx.x, lane = tid & 63, w = tid >> 6;
  const int idx = blockIdx.x;            // 0..511
  const int qt = 63 - (idx >> 3);        // LPT: big qt first
  const int b = (idx >> 1) & 3;
  const int half = idx & 1;
  const int nkt = qt + 1;
  const int kt0 = half ? (nkt >> 1) : 0;
  const int kt1 = half ? nkt : (nkt >> 1);
  const int q0 = qt * 64;

  const unsigned short* Qb  = qg  + (size_t)b * 4096 * 512;
  const unsigned short* Kb  = kg  + (size_t)b * 4096 * 512;
  const unsigned short* Vtb = vtg + (size_t)b * 512 * 4096;

  const int wr = w & 3, wc = w >> 2, g = lane >> 4, dw = w * 64;
  const int rbase = 16 * wr + 4 * g;     // this lane's 4 S-rows: rbase+j

  // Q hoist (already scaled by scale*log2e): 16 x short8 = 64 VGPR
  short8 qreg[16];
  {
    const unsigned short* qrow = Qb + (size_t)(q0 + 16 * wr + (lane & 15)) * 512 + (lane >> 4) * 8;
    #pragma unroll
    for (int ks = 0; ks < 16; ++ks)
      qreg[ks] = *reinterpret_cast<const short8*>(qrow + ks * 32);
  }

  const f32x4 z4 = {0.f, 0.f, 0.f, 0.f};
  f32x4 oacc[4][4];
  #pragma unroll
  for (int fr = 0; fr < 4; ++fr)
    #pragma unroll
    for (int fc = 0; fc < 4; ++fc) oacc[fr][fc] = z4;

  float l_run[4];
  #pragma unroll
  for (int j = 0; j < 4; ++j) l_run[j] = 0.f;

  short8 vreg[2][4];
  f32x4 sacc_cur[2], sacc_nxt[2];

#define STAGE_K(kt_) do {                                                                \
    _Pragma("unroll")                                                                    \
    for (int r8 = 0; r8 < 8; ++r8) {                                                     \
      const int r_ = r8 * 8 + w;                                                         \
      const unsigned short* g_ = Kb + (size_t)((kt_) * 64 + r_) * 512 + (lane ^ (r_ & 7)) * 8; \
      __builtin_amdgcn_global_load_lds((GLD_AS1)g_, (GLD_AS3)&Ks[(kt_) & 1][r_ * 512], 16, 0, 0); \
    }                                                                                    \
  } while (0)

#define QK_TILE(buf_, S_) do {                                                           \
    _Pragma("unroll")                                                                    \
    for (int ks = 0; ks < 16; ++ks) {                                                    \
      const int ck = ks * 4 + (lane >> 4);                                               \
      _Pragma("unroll")                                                                  \
      for (int fc = 0; fc < 2; ++fc) {                                                   \
        const int rl = 32 * wc + 16 * fc + (lane & 15);                                  \
        const short8 bv = *reinterpret_cast<const short8*>(                              \
            &Ks[buf_][rl * 512 + ((ck ^ (rl & 7)) << 3)]);                               \
        S_[fc] = __builtin_amdgcn_mfma_f32_16x16x32_bf16(qreg[ks], bv, S_[fc], 0, 0, 0); \
      }                                                                                  \
    }                                                                                    \
  } while (0)

#define PV_STEP(pb_) do {                                                                \
    _Pragma("unroll")                                                                    \
    for (int ks = 0; ks < 2; ++ks) {                                                     \
      short8 av[4];                                                                      \
      _Pragma("unroll")                                                                  \
      for (int fr = 0; fr < 4; ++fr)                                                     \
        av[fr] = *reinterpret_cast<const short8*>(                                       \
            &P_lds[pb_][16 * fr + (lane & 15)][ks * 32 + (lane >> 4) * 8]);              \
      __builtin_amdgcn_s_setprio(1);                                                     \
      _Pragma("unroll")                                                                  \
      for (int fr = 0; fr < 4; ++fr)                                                     \
        _Pragma("unroll")                                                                \
        for (int fc = 0; fc < 4; ++fc)                                                   \
          oacc[fr][fc] = __builtin_amdgcn_mfma_f32_16x16x32_bf16(av[fr], vreg[ks][fc],   \
                                                                 oacc[fr][fc], 0, 0, 0);\
      __builtin_amdgcn_s_setprio(0);                                                     \
    }                                                                                    \
  } while (0)

  if (kt0 < kt1) {
    // ---- prologue ----
    STAGE_K(kt0);
    const bool two = (kt0 + 1 < kt1);
    if (two) STAGE_K(kt0 + 1);
    FENCE();
    if (two) { asm volatile("s_waitcnt vmcnt(8)" ::: "memory"); }
    else     { asm volatile("s_waitcnt vmcnt(0)" ::: "memory"); }
    FENCE();
    __builtin_amdgcn_s_barrier();
    FENCE();
    sacc_cur[0] = z4; sacc_cur[1] = z4;
    QK_TILE(kt0 & 1, sacc_cur);
    // full drain once: covers stage(kt0+1) so the loop's QK(kt0+1) is safe, and
    // protects Ks[kt0&1] from the loop's first stage.
    BAR_VM0();

    for (int t = kt0; t < kt1; ++t) {
      // 1) stage(t+2) -> Ks[t&1]; pinned first in vm issue order
      if (t + 2 < kt1) STAGE_K(t + 2);
      FENCE();
      // 2) PV(t-1): consumes vreg = V(t-1) BEFORE it is overwritten below
      if (t > kt0) PV_STEP((t - 1) & 1);
      // 3) causal mask (diagonal tile only)
      if (t == qt) {
        #pragma unroll
        for (int fc = 0; fc < 2; ++fc) {
          const int col = 32 * wc + 16 * fc + (lane & 15);
          #pragma unroll
          for (int j = 0; j < 4; ++j)
            if (col > rbase + j) sacc_cur[fc][j] = -1e30f;
        }
      }
      // 4) softmax (no-max, exp2 domain) -> P_lds[t&1]
      {
        const int colb = 32 * wc + (lane & 15);
        #pragma unroll
        for (int j = 0; j < 4; ++j) {
          const float p0 = __builtin_amdgcn_exp2f(sacc_cur[0][j]);
          const float p1 = __builtin_amdgcn_exp2f(sacc_cur[1][j]);
          l_run[j] += p0 + p1;
          P_lds[t & 1][rbase + j][colb]      = f2bf(p0);
          P_lds[t & 1][rbase + j][colb + 16] = f2bf(p1);
        }
      }
      // 5) V(t) -> vreg issue (stays in flight across this iter's barrier)
      const int kv0 = t * 64;
      #pragma unroll
      for (int ks = 0; ks < 2; ++ks)
        #pragma unroll
        for (int fc = 0; fc < 4; ++fc)
          vreg[ks][fc] = *reinterpret_cast<const short8*>(
              Vtb + (size_t)(dw + 16 * fc + (lane & 15)) * 4096 + kv0 + ks * 32 + (lane >> 4) * 8);
      // 6) QK(t+1) from Ks[(t+1)&1] (staged at iter t-1, drained at its barrier)
      if (t + 1 < kt1) {
        sacc_nxt[0] = z4; sacc_nxt[1] = z4;
        __builtin_amdgcn_s_setprio(1);
        QK_TILE((t + 1) & 1, sacc_nxt);
        __builtin_amdgcn_s_setprio(0);
        sacc_cur[0] = sacc_nxt[0]; sacc_cur[1] = sacc_nxt[1];
      }
      // 7) single barrier: drain stage(t+2) (oldest 8), keep V(t) in flight
      BAR_VM8();
    }
    // tail: PV for the last tile
    PV_STEP((kt1 - 1) & 1);
  }

  // ---- epilogue: reduce l across 16 lanes, then across wc; write O' and (m=0,l) ----
  #pragma unroll
  for (int j = 0; j < 4; ++j) {
    l_run[j] += __shfl_xor(l_run[j], 1);
    l_run[j] += __shfl_xor(l_run[j], 2);
    l_run[j] += __shfl_xor(l_run[j], 4);
    l_run[j] += __shfl_xor(l_run[j], 8);
  }
  if ((lane & 15) == 0) {
    f32x4 l4 = {l_run[0], l_run[1], l_run[2], l_run[3]};
    *reinterpret_cast<f32x4*>(&psums[wc][rbase]) = l4;
  }
  __syncthreads();
  if ((lane & 15) == 0 && wc == 0) {
    const int rg = b * 4096 + q0 + rbase;
    const f32x4 la = *reinterpret_cast<const f32x4*>(&psums[0][rbase]);
    const f32x4 lb = *reinterpret_cast<const f32x4*>(&psums[1][rbase]);
    f32x4 m4 = {0.f, 0.f, 0.f, 0.f};   // fixed log2-domain max
    f32x4 l4 = {la[0] + lb[0], la[1] + lb[1], la[2] + lb[2], la[3] + lb[3]};
    *reinterpret_cast<f32x4*>(&ml[(half * 2) * 16384 + rg])     = m4;
    *reinterpret_cast<f32x4*>(&ml[(half * 2 + 1) * 16384 + rg]) = l4;
  }
  if (half == 0) {
    float* ob = out0 + (size_t)b * 4096 * 512;
    #pragma unroll
    for (int fr = 0; fr < 4; ++fr)
      #pragma unroll
      for (int j = 0; j < 4; ++j) {
        const int row = 16 * fr + (lane >> 4) * 4 + j;
        #pragma unroll
        for (int fc = 0; fc < 4; ++fc)
          ob[(size_t)(q0 + row) * 512 + dw + 16 * fc + (lane & 15)] = oacc[fr][fc][j];
      }
  } else {
    unsigned short* ob = out1 + (size_t)b * 4096 * 512;
    #pragma unroll
    for (int fr = 0; fr < 4; ++fr)
      #pragma unroll
      for (int j = 0; j < 4; ++j) {
        const int row = 16 * fr + (lane >> 4) * 4 + j;
        #pragma unroll
        for (int fc = 0; fc < 4; ++fc)
          ob[(size_t)(q0 + row) * 512 + dw + 16 * fc + (lane & 15)] = f2bf(oacc[fr][fc][j]);
      }
  }
#undef STAGE_K
#undef QK_TILE
#undef PV_STEP
}

// ---------------- merge the two KV-halves ----------------
// m0 == m1 == 0 by construction (no-max softmax) -> out = (v0 + v1) / (l0 + l1).
__global__ void attn_merge(float* __restrict__ out, const unsigned short* __restrict__ o1,
                           const float* __restrict__ ml) {
  const int total = 16384 * 128;  // float4 granules
  int i = blockIdx.x * blockDim.x + threadIdx.x;
  const int st = gridDim.x * blockDim.x;
  for (; i < total; i += st) {
    const int r = i >> 7;
    const float l0 = ml[16384 + r];
    const float l1 = ml[3 * 16384 + r];
    const float inv = 1.0f / (l0 + l1);  // half1 includes diagonal -> l1 > 0
    float4 v0 = reinterpret_cast<const float4*>(out)[i];
    ushort4 v1 = reinterpret_cast<const ushort4*>(o1)[i];
    float4 o;
    o.x = (v0.x + bf2f(v1.x)) * inv;
    o.y = (v0.y + bf2f(v1.y)) * inv;
    o.z = (v0.z + bf2f(v1.z)) * inv;
    o.w = (v0.w + bf2f(v1.w)) * inv;
    reinterpret_cast<float4*>(out)[i] = o;
  }
}

extern "C" void kernel_launch(void* const* d_in, const int* in_sizes, int n_in,
                              void* d_out, int out_size, void* d_ws, size_t ws_size,
                              hipStream_t stream) {
  const float* x  = (const float*)d_in[0];
  const float* wq = (const float*)d_in[1];
  const float* wk = (const float*)d_in[2];
  const float* wv = (const float*)d_in[3];

  // workspace layout (~68MB):
  // [0,16MB)    x bf16 [16384][512]  -- later REUSED as half1 partial O' (bf16)
  // [16,17.5MB) Wcat bf16 [1536][512]
  // [18,19MB)   ml float [4][16384]
  // [20,36MB)   Q bf16   [36,52MB) K bf16   [52,68MB) V^T bf16 [b][d][s]
  char* ws = (char*)d_ws;
  unsigned short* xb   = (unsigned short*)(ws);
  unsigned short* wcat = (unsigned short*)(ws + (16u << 20));
  float*          mlp  = (float*)(ws + (18u << 20));
  unsigned short* qb   = (unsigned short*)(ws + (20u << 20));
  unsigned short* kb   = (unsigned short*)(ws + (36u << 20));
  unsigned short* vtb  = (unsigned short*)(ws + (52u << 20));

  cvt_all<<<2048, 256, 0, stream>>>(x, wq, wk, wv, xb, wcat);

  qkv_gemm<<<dim3(12, 128), 256, 0, stream>>>(xb, wcat, qb, kb, vtb);

  // split-KV attention (R13/R15 structure): 512 LPT blocks + merge.
  attn_fwd<<<512, 512, 0, stream>>>(qb, kb, vtb, (float*)d_out, xb, mlp);
  attn_merge<<<2048, 256, 0, stream>>>((float*)d_out, xb, mlp);
}